// Round 1
// baseline (955.436 us; speedup 1.0000x reference)
//
#include <hip/hip_runtime.h>

#define KNN    8
#define BLOCK  256
#define TILE   2048
#define GD     32              // grid cells per axis
#define NC     (GD*GD*GD)      // 32768 cells
#define EPSW   1e-8f
#define BIGF   3.4e38f

// Sorted-descending top-8 insert; all indices compile-time -> stays in VGPRs.
__device__ __forceinline__ void insert8(float d2, int j, float bd[KNN], int bi[KNN]) {
    if (d2 < bd[0]) {
        bd[0] = d2; bi[0] = j;
#pragma unroll
        for (int t = 0; t < KNN - 1; t++) {
            if (bd[t] < bd[t + 1]) {
                float td = bd[t]; bd[t] = bd[t + 1]; bd[t + 1] = td;
                int   ti = bi[t]; bi[t] = bi[t + 1]; bi[t + 1] = ti;
            }
        }
    }
}

// ---------------- grid build ----------------

__global__ __launch_bounds__(256) void zero2(int* a, int* b) {
    int i = blockIdx.x * 256 + threadIdx.x;
    if (i < NC) { a[i] = 0; b[i] = 0; }
}

// Single-block bbox over refs -> bb[0..2]=min, bb[3..5]=G/width, bb[6]=h_min.
__global__ __launch_bounds__(1024) void bbox_kernel(const float* __restrict__ r, int M,
                                                    float* __restrict__ bb) {
    __shared__ float smn[3][1024];
    __shared__ float smx[3][1024];
    float mn0 = BIGF, mn1 = BIGF, mn2 = BIGF;
    float mx0 = -BIGF, mx1 = -BIGF, mx2 = -BIGF;
    for (int j = threadIdx.x; j < M; j += 1024) {
        float x = r[3 * j], y = r[3 * j + 1], z = r[3 * j + 2];
        mn0 = fminf(mn0, x); mx0 = fmaxf(mx0, x);
        mn1 = fminf(mn1, y); mx1 = fmaxf(mx1, y);
        mn2 = fminf(mn2, z); mx2 = fmaxf(mx2, z);
    }
    int t = threadIdx.x;
    smn[0][t] = mn0; smn[1][t] = mn1; smn[2][t] = mn2;
    smx[0][t] = mx0; smx[1][t] = mx1; smx[2][t] = mx2;
    __syncthreads();
    for (int o = 512; o > 0; o >>= 1) {
        if (t < o) {
#pragma unroll
            for (int a = 0; a < 3; a++) {
                smn[a][t] = fminf(smn[a][t], smn[a][t + o]);
                smx[a][t] = fmaxf(smx[a][t], smx[a][t + o]);
            }
        }
        __syncthreads();
    }
    if (t == 0) {
        float hmin = BIGF;
#pragma unroll
        for (int a = 0; a < 3; a++) {
            float w = fmaxf(smx[a][0] - smn[a][0], 1e-9f);
            bb[a] = smn[a][0];
            bb[3 + a] = (float)GD / w;
            hmin = fminf(hmin, w / (float)GD);
        }
        bb[6] = hmin;
    }
}

__device__ __forceinline__ int cell_clamp(int c) {
    return c < 0 ? 0 : (c > GD - 1 ? GD - 1 : c);
}

__device__ __forceinline__ int cell_of(float x, float y, float z, const float* bb) {
    int cx = cell_clamp((int)((x - bb[0]) * bb[3]));
    int cy = cell_clamp((int)((y - bb[1]) * bb[4]));
    int cz = cell_clamp((int)((z - bb[2]) * bb[5]));
    return (cz * GD + cy) * GD + cx;
}

// Histogram refs AND queries in one dispatch (items 0..M-1 = refs, M..M+N-1 = queries).
__global__ __launch_bounds__(256) void hist2(const float* __restrict__ r,
                                             const float* __restrict__ q,
                                             int M, int N, const float* __restrict__ bb,
                                             int* __restrict__ rcid, int* __restrict__ qcid,
                                             int* __restrict__ rcnt, int* __restrict__ qcnt) {
    int i = blockIdx.x * 256 + threadIdx.x;
    if (i < M) {
        int cid = cell_of(r[3 * i], r[3 * i + 1], r[3 * i + 2], bb);
        rcid[i] = cid;
        atomicAdd(rcnt + cid, 1);
    } else if (i < M + N) {
        int j = i - M;
        int cid = cell_of(q[3 * j], q[3 * j + 1], q[3 * j + 2], bb);
        qcid[j] = cid;
        atomicAdd(qcnt + cid, 1);
    }
}

// Exclusive scan of NC cell counts; block 0 -> refs, block 1 -> queries.
// Writes start[] (NC+1 entries) and turns cnt[] into scatter cursors (= start).
__global__ __launch_bounds__(1024) void scan2(int* __restrict__ rcnt, int* __restrict__ rstart,
                                              int* __restrict__ qcnt, int* __restrict__ qstart) {
    int* cnt = (blockIdx.x == 0) ? rcnt : qcnt;
    int* st  = (blockIdx.x == 0) ? rstart : qstart;
    __shared__ int part[1024];
    int t = threadIdx.x;
    int base = t * 32;
    int s = 0;
#pragma unroll
    for (int k = 0; k < 32; k++) s += cnt[base + k];
    part[t] = s;
    __syncthreads();
    for (int off = 1; off < 1024; off <<= 1) {
        int v = (t >= off) ? part[t - off] : 0;
        __syncthreads();
        part[t] += v;
        __syncthreads();
    }
    int run = part[t] - s;   // exclusive prefix of this thread's chunk
#pragma unroll
    for (int k = 0; k < 32; k++) {
        int c = cnt[base + k];       // own cells only: safe to read-then-overwrite
        st[base + k] = run;
        cnt[base + k] = run;         // cursor = start
        run += c;
    }
    if (t == 1023) st[NC] = run;     // total
}

// Scatter refs into cell-sorted packed float4 (x,y,z,|r|^2) + orig-index map;
// scatter query ids into cell-sorted processing order.
__global__ __launch_bounds__(256) void scatter2(const float* __restrict__ r, int M, int N,
                                                const int* __restrict__ rcid,
                                                const int* __restrict__ qcid,
                                                int* __restrict__ rcur, int* __restrict__ qcur,
                                                float4* __restrict__ rps, int* __restrict__ sidx,
                                                int* __restrict__ qorder) {
    int i = blockIdx.x * 256 + threadIdx.x;
    if (i < M) {
        int pos = atomicAdd(rcur + rcid[i], 1);
        float x = r[3 * i], y = r[3 * i + 1], z = r[3 * i + 2];
        rps[pos] = make_float4(x, y, z, x * x + y * y + z * z);
        sidx[pos] = i;
    } else if (i < M + N) {
        int j = i - M;
        int pos = atomicAdd(qcur + qcid[j], 1);
        qorder[pos] = j;
    }
}

// ---------------- main grid-KNN kernel ----------------
// Per lane: one query (cell-sorted order -> wave-coherent cells). Expanding
// Chebyshev shells; any unscanned cell after ring R is >= R*h_min away, so
// stop when thr <= (R*h_min)^2. Exact same d2 expression as the verified
// brute-force kernel -> identical selection numerics.
__global__ __launch_bounds__(256) void knn_grid(
    const float4* __restrict__ rps, const int* __restrict__ rstart,
    const int* __restrict__ qorder, const float* __restrict__ q,
    const int* __restrict__ sidx, const float* __restrict__ f,
    const float* __restrict__ bb, float* __restrict__ out, int N) {
    int t = blockIdx.x * 256 + threadIdx.x;
    if (t >= N) return;
    int qi = qorder[t];
    float qx = q[3 * qi], qy = q[3 * qi + 1], qz = q[3 * qi + 2];
    float q2 = qx * qx + qy * qy + qz * qz;
    float mnx = bb[0], mny = bb[1], mnz = bb[2];
    float ihx = bb[3], ihy = bb[4], ihz = bb[5], hmin = bb[6];
    int cx = cell_clamp((int)((qx - mnx) * ihx));
    int cy = cell_clamp((int)((qy - mny) * ihy));
    int cz = cell_clamp((int)((qz - mnz) * ihz));

    float bd[KNN]; int bi[KNN];
#pragma unroll
    for (int k = 0; k < KNN; k++) { bd[k] = BIGF; bi[k] = 0; }
    float thr = BIGF;
    bool done = false;

    for (int R = 0; R < GD; ++R) {
        if (!done) {
            for (int dz = -R; dz <= R; ++dz) {
                int z = cz + dz;
                if ((unsigned)z >= GD) continue;
                for (int dy = -R; dy <= R; ++dy) {
                    int y = cy + dy;
                    if ((unsigned)y >= GD) continue;
                    bool face = (dz == -R) | (dz == R) | (dy == -R) | (dy == R);
                    int step = face ? 1 : 2 * R;   // interior rows: only dx = +/-R
                    for (int dx = -R; dx <= R; dx += step) {
                        int x = cx + dx;
                        if ((unsigned)x >= GD) continue;
                        int cid = (z * GD + y) * GD + x;
                        int s = rstart[cid], e = rstart[cid + 1];
                        for (int ii = s; ii < e; ++ii) {
                            float4 p = rps[ii];
                            float d2 = (q2 + p.w) - 2.0f * (qx * p.x + qy * p.y + qz * p.z);
                            if (d2 < thr) { insert8(d2, ii, bd, bi); thr = bd[0]; }
                        }
                    }
                }
            }
            float lb = (float)R * hmin;
            if (thr <= lb * lb) done = true;
        }
        if (__all(done)) break;
    }

    float wsum = 0.f, ox = 0.f, oy = 0.f, oz = 0.f;
#pragma unroll
    for (int k = 0; k < KNN; k++) {
        float w = 1.0f / (fmaxf(bd[k], 0.0f) + EPSW);
        int j = sidx[bi[k]];
        wsum += w;
        ox += w * f[3 * j];
        oy += w * f[3 * j + 1];
        oz += w * f[3 * j + 2];
    }
    float inv = 1.0f / wsum;
    out[3 * qi]     = ox * inv;
    out[3 * qi + 1] = oy * inv;
    out[3 * qi + 2] = oz * inv;
}

// ---------- fallback (ws too small): R1 fused single-pass brute force ----------
__global__ __launch_bounds__(BLOCK) void knn_fused(
    const float* __restrict__ q, const float* __restrict__ r,
    const float* __restrict__ f, float* __restrict__ out, int N, int M) {
    __shared__ float4 lds[TILE];
    int qi = blockIdx.x * BLOCK + threadIdx.x;
    float qx = 0.f, qy = 0.f, qz = 0.f, q2 = 0.f;
    if (qi < N) {
        qx = q[3 * qi]; qy = q[3 * qi + 1]; qz = q[3 * qi + 2];
        q2 = qx * qx + qy * qy + qz * qz;
    }
    float bd[KNN]; int bi[KNN];
#pragma unroll
    for (int k = 0; k < KNN; k++) { bd[k] = BIGF; bi[k] = 0; }
    for (int tb = 0; tb < M; tb += TILE) {
        int cnt = min(TILE, M - tb);
        for (int i = threadIdx.x; i < cnt; i += BLOCK) {
            int j = tb + i;
            float rx = r[3 * j], ry = r[3 * j + 1], rz = r[3 * j + 2];
            lds[i] = make_float4(rx, ry, rz, rx * rx + ry * ry + rz * rz);
        }
        __syncthreads();
        for (int i = 0; i < cnt; i++) {
            float4 p = lds[i];
            float d2 = (q2 + p.w) - 2.0f * (qx * p.x + qy * p.y + qz * p.z);
            insert8(d2, tb + i, bd, bi);
        }
        __syncthreads();
    }
    if (qi < N) {
        float wsum = 0.f, ox = 0.f, oy = 0.f, oz = 0.f;
#pragma unroll
        for (int k = 0; k < KNN; k++) {
            float w = 1.0f / (fmaxf(bd[k], 0.0f) + EPSW);
            int j = bi[k];
            ox += w * f[3 * j];
            oy += w * f[3 * j + 1];
            oz += w * f[3 * j + 2];
        }
        float inv = 1.0f / wsum;
        out[3 * qi]     = ox * inv;
        out[3 * qi + 1] = oy * inv;
        out[3 * qi + 2] = oz * inv;
    }
}

extern "C" void kernel_launch(void* const* d_in, const int* in_sizes, int n_in,
                              void* d_out, int out_size, void* d_ws, size_t ws_size,
                              hipStream_t stream) {
    const float* q = (const float*)d_in[0];
    const float* r = (const float*)d_in[1];
    const float* f = (const float*)d_in[2];
    float* out = (float*)d_out;
    int N = in_sizes[0] / 3;
    int M = in_sizes[1] / 3;

    // workspace layout (256B-aligned slots), ~1.2 MB total
    size_t off = 0;
    auto take = [&](size_t b) { size_t o = off; off += (b + 255) & ~(size_t)255; return o; };
    size_t o_rps  = take((size_t)M * 16);
    size_t o_sidx = take((size_t)M * 4);
    size_t o_rcid = take((size_t)M * 4);
    size_t o_qcid = take((size_t)N * 4);
    size_t o_qord = take((size_t)N * 4);
    size_t o_rst  = take((size_t)(NC + 1) * 4);
    size_t o_rcur = take((size_t)NC * 4);
    size_t o_qst  = take((size_t)(NC + 1) * 4);
    size_t o_qcur = take((size_t)NC * 4);
    size_t o_bb   = take(32);

    int grid_x = (N + BLOCK - 1) / BLOCK;
    if (off <= ws_size) {
        char* w = (char*)d_ws;
        float4* rps  = (float4*)(w + o_rps);
        int* sidx    = (int*)(w + o_sidx);
        int* rcid    = (int*)(w + o_rcid);
        int* qcid    = (int*)(w + o_qcid);
        int* qorder  = (int*)(w + o_qord);
        int* rstart  = (int*)(w + o_rst);
        int* rcur    = (int*)(w + o_rcur);
        int* qstart  = (int*)(w + o_qst);
        int* qcur    = (int*)(w + o_qcur);
        float* bb    = (float*)(w + o_bb);

        int g_all = (M + N + 255) / 256;
        zero2<<<(NC + 255) / 256, 256, 0, stream>>>(rcur, qcur);
        bbox_kernel<<<1, 1024, 0, stream>>>(r, M, bb);
        hist2<<<g_all, 256, 0, stream>>>(r, q, M, N, bb, rcid, qcid, rcur, qcur);
        scan2<<<2, 1024, 0, stream>>>(rcur, rstart, qcur, qstart);
        scatter2<<<g_all, 256, 0, stream>>>(r, M, N, rcid, qcid, rcur, qcur, rps, sidx, qorder);
        knn_grid<<<grid_x, 256, 0, stream>>>(rps, rstart, qorder, q, sidx, f, bb, out, N);
    } else {
        knn_fused<<<grid_x, BLOCK, 0, stream>>>(q, r, f, out, N, M);
    }
}